// Round 4
// baseline (324.684 us; speedup 1.0000x reference)
//
#include <hip/hip_runtime.h>
#include <math.h>

// ComplexEMA: y[b,d,t] = Re(sum_n gam_dn * h_dn[t]) + omega_d * x[b,d,t]
//             h[t] = q*h[t-1] + p*x[t]  (diagonal complex recurrence)
// u = h/p:  u' = q*u + x,  h = p*u, gam' = p*gam.
// State kept as (ur, vi) with vi = -ui ("negated imag") so the complex
// update needs NO component swaps:
//   s   = qi*ur
//   ur' = qr*ur + qi*vi + x
//   vi' = qr*vi - s
//   Re(gam*h) = gr*ur + gv*vi   with gr = p*S*g0, gv = p*S*g1
// 3-pass chunked scan (exact): C chunks of CH steps over L=4096.
// C=64 if ws fits (32 MB F buffer), else C=32. Coeffs computed per-block
// in LDS (no separate coeff kernel). y stored non-temporal in 64B bursts.

constexpr int kD = 2048, kN = 16, kB = 2, kL = 4096;
constexpr float kSCALE = 0.25f;    // sqrt(1/N)

typedef float v2 __attribute__((ext_vector_type(2)));
typedef float v4 __attribute__((ext_vector_type(4)));   // native vec for nontemporal store

static __device__ __forceinline__ v2 mkv2(float a, float b) {
    v2 r; r.x = a; r.y = b; return r;
}

static __device__ __forceinline__ v2 v2fma(v2 a, v2 b, v2 c) {
#if __has_builtin(__builtin_elementwise_fma)
    return __builtin_elementwise_fma(a, b, c);
#else
    v2 r;
    r.x = __builtin_fmaf(a.x, b.x, c.x);
    r.y = __builtin_fmaf(a.y, b.y, c.y);
    return r;
#endif
}

static __device__ __forceinline__ void sigmoid_coeffs(
        const float* __restrict__ alpha, const float* __restrict__ delta,
        const float* __restrict__ theta, int d, int n,
        float& qr, float& qi, float& p) {
    int i = d * kN + n;
    p        = 1.0f / (1.0f + expf(-alpha[i]));
    float dd = 1.0f / (1.0f + expf(-delta[i]));
    float th = 1.0f / (1.0f + expf(-theta[d]));
    float phi = (float)(n + 1) * th * 0.39269908169872414f;  // 2*pi/16
    float r = 1.0f - p * dd;
    float s, c;
    sincosf(phi, &s, &c);
    qr = r * c;
    qi = r * s;
}

// F record per (row, chunk): 8 pairs x float4 (ur_2j, ur_2j+1, vi_2j, vi_2j+1)

// Pass 1: local chunk recurrence from zero init; write end-state F.
template <int C>
__global__ __launch_bounds__(256) void pass1_kernel(
        const float* __restrict__ x,
        const float* __restrict__ alpha, const float* __restrict__ delta,
        const float* __restrict__ theta, float* __restrict__ F) {
    constexpr int CH = kL / C;         // steps per chunk
    constexpr int RPB = 256 / C;       // rows per block
    constexpr int NSI = CH / 16;       // 16-step super-iterations
    __shared__ float qrS[RPB][kN], qiS[RPB][kN];

    int t = threadIdx.x;
    int row0 = blockIdx.x * RPB;
    if (t < RPB * kN) {
        int lr = t / kN, n = t % kN;
        int d = (row0 + lr) & (kD - 1);
        float qr, qi, p;
        sigmoid_coeffs(alpha, delta, theta, d, n, qr, qi, p);
        qrS[lr][n] = qr;
        qiS[lr][n] = qi;
    }
    __syncthreads();

    int lr = t / C, c = t % C;
    int row = row0 + lr;
    v2 qr[8], qi[8], ur[8], vi[8];
    const v2* qrp = (const v2*)qrS[lr];
    const v2* qip = (const v2*)qiS[lr];
#pragma unroll
    for (int j = 0; j < 8; j++) {
        qr[j] = qrp[j]; qi[j] = qip[j];
        ur[j] = mkv2(0.0f, 0.0f); vi[j] = mkv2(0.0f, 0.0f);
    }

    const float4* xp = (const float4*)(x + (size_t)row * kL + (size_t)c * CH);
    float4 buf[4];
#pragma unroll
    for (int k = 0; k < 4; k++) buf[k] = xp[k];
#pragma unroll 1
    for (int ii = 0; ii < NSI; ii++) {
        int nb = (ii + 1 < NSI) ? ii + 1 : ii;
        float4 nxt[4];
#pragma unroll
        for (int k = 0; k < 4; k++) nxt[k] = xp[nb * 4 + k];  // prefetch
        float xs[16];
#pragma unroll
        for (int k = 0; k < 4; k++) {
            xs[4*k+0]=buf[k].x; xs[4*k+1]=buf[k].y; xs[4*k+2]=buf[k].z; xs[4*k+3]=buf[k].w;
        }
#pragma unroll
        for (int jstep = 0; jstep < 16; jstep++) {
            v2 xx = mkv2(xs[jstep], xs[jstep]);
#pragma unroll
            for (int j = 0; j < 8; j++) {
                v2 s = qi[j] * ur[j];
                v2 tt = v2fma(qr[j], ur[j], xx);
                ur[j] = v2fma(qi[j], vi[j], tt);
                vi[j] = v2fma(qr[j], vi[j], -s);
            }
        }
#pragma unroll
        for (int k = 0; k < 4; k++) buf[k] = nxt[k];
    }

    float4* Fp = (float4*)(F + ((size_t)row * C + c) * 32);
#pragma unroll
    for (int j = 0; j < 8; j++)
        Fp[j] = make_float4(ur[j].x, ur[j].y, vi[j].x, vi[j].y);
}

// Pass 2: combine chunk end-states; write chunk-initial states in place + h_out.
// One thread per (row, mode-pair j): 2 modes, float4-coalesced.
template <int C>
__global__ void pass2_kernel(const float* __restrict__ alpha,
                             const float* __restrict__ delta,
                             const float* __restrict__ theta,
                             float* __restrict__ FH,
                             float* __restrict__ hout) {
    constexpr int CH = kL / C;
    constexpr int LOG = (CH == 64) ? 6 : 7;
    int idx = blockIdx.x * 256 + threadIdx.x;   // row*8 + j
    if (idx >= kB * kD * 8) return;
    int j = idx & 7, row = idx >> 3, d = row & (kD - 1);
    float a0r, a0i, p0, a1r, a1i, p1;
    sigmoid_coeffs(alpha, delta, theta, d, 2 * j,     a0r, a0i, p0);
    sigmoid_coeffs(alpha, delta, theta, d, 2 * j + 1, a1r, a1i, p1);
    // q^CH by repeated squaring
#pragma unroll
    for (int k = 0; k < LOG; k++) {
        float n0r = a0r * a0r - a0i * a0i, n0i = 2.0f * a0r * a0i;
        float n1r = a1r * a1r - a1i * a1i, n1i = 2.0f * a1r * a1i;
        a0r = n0r; a0i = n0i; a1r = n1r; a1i = n1i;
    }
    float H0r = 0.0f, H0i = 0.0f, H1r = 0.0f, H1i = 0.0f;
    float* base = FH + (size_t)row * C * 32 + j * 4;
#pragma unroll 1
    for (int c = 0; c < C; c++) {
        float4 f = *(float4*)(base + (size_t)c * 32);
        float F0r = f.x, F1r = f.y, F0i = -f.z, F1i = -f.w;  // vi = -ui
        *(float4*)(base + (size_t)c * 32) = make_float4(H0r, H1r, -H0i, -H1i);
        float n0r = __builtin_fmaf(a0r, H0r, __builtin_fmaf(-a0i, H0i, F0r));
        float n0i = __builtin_fmaf(a0r, H0i, __builtin_fmaf( a0i, H0r, F0i));
        float n1r = __builtin_fmaf(a1r, H1r, __builtin_fmaf(-a1i, H1i, F1r));
        float n1i = __builtin_fmaf(a1r, H1i, __builtin_fmaf( a1i, H1r, F1i));
        H0r = n0r; H0i = n0i; H1r = n1r; H1i = n1i;
    }
    // h = p * u ; hout layout (B,D,N,2) -> row*32 + n*2
    float4* hp = (float4*)(hout + (size_t)row * 32 + j * 4);
    *hp = make_float4(p0 * H0r, p0 * H0i, p1 * H1r, p1 * H1i);
}

// Pass 3: rerun recurrence from correct init, emit y (non-temporal bursts).
template <int C>
__global__ __launch_bounds__(256) void pass3_kernel(
        const float* __restrict__ x,
        const float* __restrict__ alpha, const float* __restrict__ delta,
        const float* __restrict__ theta, const float* __restrict__ gamma,
        const float* __restrict__ omega,
        const float* __restrict__ H, float* __restrict__ y) {
    constexpr int CH = kL / C;
    constexpr int RPB = 256 / C;
    constexpr int NSI = CH / 16;
    __shared__ float qrS[RPB][kN], qiS[RPB][kN], grS[RPB][kN], gvS[RPB][kN];
    __shared__ float omS[RPB];

    int t = threadIdx.x;
    int row0 = blockIdx.x * RPB;
    if (t < RPB * kN) {
        int lr = t / kN, n = t % kN;
        int d = (row0 + lr) & (kD - 1);
        float qr, qi, p;
        sigmoid_coeffs(alpha, delta, theta, d, n, qr, qi, p);
        int i = d * kN + n;
        qrS[lr][n] = qr;
        qiS[lr][n] = qi;
        grS[lr][n] = p * kSCALE * gamma[2 * i];
        gvS[lr][n] = p * kSCALE * gamma[2 * i + 1];
        if (n == 0) omS[lr] = omega[d];
    }
    __syncthreads();

    int lr = t / C, c = t % C;
    int row = row0 + lr;
    v2 qr[8], qi[8], gr[8], gv[8], ur[8], vi[8];
    {
        const v2* qrp = (const v2*)qrS[lr];
        const v2* qip = (const v2*)qiS[lr];
        const v2* grp = (const v2*)grS[lr];
        const v2* gvp = (const v2*)gvS[lr];
#pragma unroll
        for (int j = 0; j < 8; j++) {
            qr[j] = qrp[j]; qi[j] = qip[j]; gr[j] = grp[j]; gv[j] = gvp[j];
        }
    }
    const float4* Hp = (const float4*)(H + ((size_t)row * C + c) * 32);
#pragma unroll
    for (int j = 0; j < 8; j++) {
        float4 h = Hp[j];
        ur[j] = mkv2(h.x, h.y);
        vi[j] = mkv2(h.z, h.w);
    }
    float om = omS[lr];

    const float4* xp = (const float4*)(x + (size_t)row * kL + (size_t)c * CH);
    v4*           yp = (v4*)(y + (size_t)row * kL + (size_t)c * CH);
    float4 buf[4];
#pragma unroll
    for (int k = 0; k < 4; k++) buf[k] = xp[k];
#pragma unroll 1
    for (int ii = 0; ii < NSI; ii++) {
        int nb = (ii + 1 < NSI) ? ii + 1 : ii;
        float4 nxt[4];
#pragma unroll
        for (int k = 0; k < 4; k++) nxt[k] = xp[nb * 4 + k];  // prefetch
        float xs[16], ys[16];
#pragma unroll
        for (int k = 0; k < 4; k++) {
            xs[4*k+0]=buf[k].x; xs[4*k+1]=buf[k].y; xs[4*k+2]=buf[k].z; xs[4*k+3]=buf[k].w;
        }
#pragma unroll
        for (int jstep = 0; jstep < 16; jstep++) {
            v2 xx = mkv2(xs[jstep], xs[jstep]);
            v2 a0 = mkv2(0.0f, 0.0f), a1 = mkv2(0.0f, 0.0f);
            v2 a2 = mkv2(0.0f, 0.0f), a3 = mkv2(0.0f, 0.0f);
#pragma unroll
            for (int j = 0; j < 8; j += 4) {
                v2 s, tt;
                s = qi[j] * ur[j];
                tt = v2fma(qr[j], ur[j], xx);
                ur[j] = v2fma(qi[j], vi[j], tt);
                vi[j] = v2fma(qr[j], vi[j], -s);
                a0 = v2fma(gr[j], ur[j], a0);
                a0 = v2fma(gv[j], vi[j], a0);
                s = qi[j+1] * ur[j+1];
                tt = v2fma(qr[j+1], ur[j+1], xx);
                ur[j+1] = v2fma(qi[j+1], vi[j+1], tt);
                vi[j+1] = v2fma(qr[j+1], vi[j+1], -s);
                a1 = v2fma(gr[j+1], ur[j+1], a1);
                a1 = v2fma(gv[j+1], vi[j+1], a1);
                s = qi[j+2] * ur[j+2];
                tt = v2fma(qr[j+2], ur[j+2], xx);
                ur[j+2] = v2fma(qi[j+2], vi[j+2], tt);
                vi[j+2] = v2fma(qr[j+2], vi[j+2], -s);
                a2 = v2fma(gr[j+2], ur[j+2], a2);
                a2 = v2fma(gv[j+2], vi[j+2], a2);
                s = qi[j+3] * ur[j+3];
                tt = v2fma(qr[j+3], ur[j+3], xx);
                ur[j+3] = v2fma(qi[j+3], vi[j+3], tt);
                vi[j+3] = v2fma(qr[j+3], vi[j+3], -s);
                a3 = v2fma(gr[j+3], ur[j+3], a3);
                a3 = v2fma(gv[j+3], vi[j+3], a3);
            }
            v2 sm = (a0 + a1) + (a2 + a3);
            ys[jstep] = sm.x + sm.y + om * xs[jstep];
        }
#pragma unroll
        for (int k = 0; k < 4; k++) {
            v4 o;
            o.x = ys[4*k+0]; o.y = ys[4*k+1]; o.z = ys[4*k+2]; o.w = ys[4*k+3];
            __builtin_nontemporal_store(o, yp + ii * 4 + k);   // 64B burst/lane
        }
#pragma unroll
        for (int k = 0; k < 4; k++) buf[k] = nxt[k];
    }
}

template <int C>
static void launch_all(const float* x, const float* alpha, const float* delta,
                       const float* theta, const float* gamma, const float* omega,
                       float* y, float* hout, float* F, hipStream_t stream) {
    pass1_kernel<C><<<(kB * kD * C) / 256, 256, 0, stream>>>(x, alpha, delta, theta, F);
    pass2_kernel<C><<<(kB * kD * 8 + 255) / 256, 256, 0, stream>>>(alpha, delta, theta, F, hout);
    pass3_kernel<C><<<(kB * kD * C) / 256, 256, 0, stream>>>(x, alpha, delta, theta,
                                                             gamma, omega, F, y);
}

extern "C" void kernel_launch(void* const* d_in, const int* in_sizes, int n_in,
                              void* d_out, int out_size, void* d_ws, size_t ws_size,
                              hipStream_t stream) {
    const float* x     = (const float*)d_in[0];
    const float* alpha = (const float*)d_in[1];
    const float* delta = (const float*)d_in[2];
    const float* theta = (const float*)d_in[3];
    const float* gamma = (const float*)d_in[4];
    const float* omega = (const float*)d_in[5];
    float* y    = (float*)d_out;
    float* hout = y + (size_t)kB * kD * kL;      // (B,D,N,2) after y
    float* F    = (float*)d_ws;

    size_t need64 = (size_t)kB * kD * 64 * 32 * sizeof(float);  // 32 MB
    if (ws_size >= need64)
        launch_all<64>(x, alpha, delta, theta, gamma, omega, y, hout, F, stream);
    else
        launch_all<32>(x, alpha, delta, theta, gamma, omega, y, hout, F, stream);
}